// Round 5
// baseline (430.314 us; speedup 1.0000x reference)
//
#include <hip/hip_runtime.h>
#include <math.h>

#define N_NODES 50000
#define N_EDGES 800000
#define EMBED 256
#define HID 128
#define OUTD 12
#define N_TGT 4096

#define SCAN_NB 196  // ceil(50000/256)

// ---------------- CSR build ----------------
__global__ void k_hist(const int* __restrict__ dst, int* __restrict__ counts, int nE) {
    int i = blockIdx.x * 256 + threadIdx.x;
    if (i < nE) atomicAdd(&counts[dst[i]], 1);
}

// stage 1: per-block sums of counts
__global__ __launch_bounds__(256) void k_scan_part(const int* __restrict__ counts,
                                                   int* __restrict__ partials) {
    __shared__ int ws[4];
    int i = blockIdx.x * 256 + threadIdx.x;
    int v = (i < N_NODES) ? counts[i] : 0;
#pragma unroll
    for (int off = 32; off > 0; off >>= 1) v += __shfl_down(v, off);
    int wid = threadIdx.x >> 6;
    if ((threadIdx.x & 63) == 0) ws[wid] = v;
    __syncthreads();
    if (threadIdx.x == 0) partials[blockIdx.x] = ws[0] + ws[1] + ws[2] + ws[3];
}

// stage 2: exclusive scan of partials[SCAN_NB] in one small block
__global__ __launch_bounds__(256) void k_scan_top(int* __restrict__ partials) {
    __shared__ int s[256];
    int tid = threadIdx.x;
    int v = (tid < SCAN_NB) ? partials[tid] : 0;
    s[tid] = v;
    __syncthreads();
#pragma unroll
    for (int off = 1; off < 256; off <<= 1) {
        int t = (tid >= off) ? s[tid - off] : 0;
        __syncthreads();
        s[tid] += t;
        __syncthreads();
    }
    if (tid < SCAN_NB) partials[tid] = s[tid] - v;  // exclusive
}

// stage 3: per-block exclusive scan + offset -> rowptr, cursor, dinv
__global__ __launch_bounds__(256) void k_scan_final(const int* __restrict__ counts,
                                                    const int* __restrict__ partials,
                                                    int* __restrict__ rowptr,
                                                    int* __restrict__ cursor,
                                                    float* __restrict__ dinv) {
    __shared__ int s[256];
    int tid = threadIdx.x;
    int i = blockIdx.x * 256 + tid;
    int c = (i < N_NODES) ? counts[i] : 0;
    s[tid] = c;
    __syncthreads();
#pragma unroll
    for (int off = 1; off < 256; off <<= 1) {
        int t = (tid >= off) ? s[tid - off] : 0;
        __syncthreads();
        s[tid] += t;
        __syncthreads();
    }
    if (i < N_NODES) {
        int rp = partials[blockIdx.x] + s[tid] - c;  // exclusive
        rowptr[i] = rp;
        cursor[i] = rp;
        dinv[i] = rsqrtf(1.0f + (float)c);
    }
}

__global__ void k_fill(const int* __restrict__ src, const int* __restrict__ dst,
                       int* __restrict__ cursor, int* __restrict__ col, int nE) {
    int i = blockIdx.x * 256 + threadIdx.x;
    if (i < nE) {
        int pos = atomicAdd(&cursor[dst[i]], 1);
        col[pos] = src[i];
    }
}

// canonicalize: sort each row's neighbor list ascending so the aggregation
// sum order is a deterministic function of the edge set (atomic fill order
// is schedule-dependent; tripwire requires bitwise-stable output).
__global__ void k_sort_rows(const int* __restrict__ rowptr, const int* __restrict__ counts,
                            int* __restrict__ col) {
    int v = blockIdx.x * 256 + threadIdx.x;
    if (v >= N_NODES) return;
    int beg = rowptr[v], cnt = counts[v];
    for (int i = 1; i < cnt; ++i) {
        int key = col[beg + i];
        int j = i - 1;
        while (j >= 0 && col[beg + j] > key) {
            col[beg + j + 1] = col[beg + j];
            --j;
        }
        col[beg + j + 1] = key;
    }
}

// ---------------- tiled f32 GEMM: H[n][128] = X[n][K] @ W[K][128] ----------------
template <int K>
__global__ __launch_bounds__(128) void k_gemm(const float* __restrict__ X,
                                              const float* __restrict__ W,
                                              float* __restrict__ H, int n) {
    __shared__ float As[32][68];
    __shared__ float Bs[32][132];
    const int tid = threadIdx.x;
    const int row0 = blockIdx.x * 64;
    const int ty = tid >> 4;
    const int tx = tid & 15;
    float acc[8][8] = {};
    for (int k0 = 0; k0 < K; k0 += 32) {
#pragma unroll
        for (int i = 0; i < 4; ++i) {
            int f = tid + i * 128;
            int r = f >> 3, k4 = f & 7;
            float4 v = make_float4(0.f, 0.f, 0.f, 0.f);
            if (row0 + r < n)
                v = *(const float4*)&X[(size_t)(row0 + r) * K + k0 + k4 * 4];
            As[k4 * 4 + 0][r] = v.x;
            As[k4 * 4 + 1][r] = v.y;
            As[k4 * 4 + 2][r] = v.z;
            As[k4 * 4 + 3][r] = v.w;
        }
#pragma unroll
        for (int i = 0; i < 8; ++i) {
            int f = tid + i * 128;
            int kk = f >> 5, c4 = f & 31;
            *(float4*)&Bs[kk][c4 * 4] = *(const float4*)&W[(size_t)(k0 + kk) * 128 + c4 * 4];
        }
        __syncthreads();
#pragma unroll
        for (int k = 0; k < 32; ++k) {
            float4 a0 = *(const float4*)&As[k][ty * 8];
            float4 a1 = *(const float4*)&As[k][ty * 8 + 4];
            float4 b0 = *(const float4*)&Bs[k][tx * 8];
            float4 b1 = *(const float4*)&Bs[k][tx * 8 + 4];
            float a[8] = {a0.x, a0.y, a0.z, a0.w, a1.x, a1.y, a1.z, a1.w};
            float b[8] = {b0.x, b0.y, b0.z, b0.w, b1.x, b1.y, b1.z, b1.w};
#pragma unroll
            for (int i = 0; i < 8; ++i)
#pragma unroll
                for (int j = 0; j < 8; ++j) acc[i][j] = fmaf(a[i], b[j], acc[i][j]);
        }
        __syncthreads();
    }
#pragma unroll
    for (int i = 0; i < 8; ++i) {
        int r = row0 + ty * 8 + i;
        if (r < n) {
            *(float4*)&H[(size_t)r * 128 + tx * 8] =
                make_float4(acc[i][0], acc[i][1], acc[i][2], acc[i][3]);
            *(float4*)&H[(size_t)r * 128 + tx * 8 + 4] =
                make_float4(acc[i][4], acc[i][5], acc[i][6], acc[i][7]);
        }
    }
}

// ---------------- fused CSR aggregation + self-loop + bias + ReLU ----------------
__global__ __launch_bounds__(256) void k_agg_csr(const float* __restrict__ h,
                                                 const int* __restrict__ rowptr,
                                                 const int* __restrict__ counts,
                                                 const int* __restrict__ col,
                                                 const float* __restrict__ dinv,
                                                 const float* __restrict__ b,
                                                 float* __restrict__ out) {
    int t = blockIdx.x * 256 + threadIdx.x;
    int v = t >> 5;
    int lane = t & 31;
    if (v >= N_NODES) return;
    float dv = dinv[v];
    float4 hv = *(const float4*)&h[(size_t)v * HID + lane * 4];
    float sl = dv * dv;
    float4 acc = make_float4(hv.x * sl, hv.y * sl, hv.z * sl, hv.w * sl);
    int beg = rowptr[v];
    int cnt = counts[v];
    for (int j = 0; j < cnt; ++j) {
        int s = col[beg + j];
        float w = dinv[s] * dv;
        float4 m = *(const float4*)&h[(size_t)s * HID + lane * 4];
        acc.x = fmaf(m.x, w, acc.x);
        acc.y = fmaf(m.y, w, acc.y);
        acc.z = fmaf(m.z, w, acc.z);
        acc.w = fmaf(m.w, w, acc.w);
    }
    float4 bv = *(const float4*)&b[lane * 4];
    acc.x = fmaxf(acc.x + bv.x, 0.f);
    acc.y = fmaxf(acc.y + bv.y, 0.f);
    acc.z = fmaxf(acc.z + bv.z, 0.f);
    acc.w = fmaxf(acc.w + bv.w, 0.f);
    *(float4*)&out[(size_t)v * HID + lane * 4] = acc;
}

// ---------------- final readout ----------------
__global__ void k_final(const float* __restrict__ h, const int* __restrict__ mask,
                        const float* __restrict__ Wr, const float* __restrict__ br,
                        float* __restrict__ out) {
    int t = blockIdx.x;
    int lane = threadIdx.x;
    int node = mask[t];
    float2 hv = *(const float2*)&h[(size_t)node * HID + lane * 2];
#pragma unroll
    for (int j = 0; j < OUTD; ++j) {
        float p = hv.x * Wr[(lane * 2) * OUTD + j] + hv.y * Wr[(lane * 2 + 1) * OUTD + j];
#pragma unroll
        for (int off = 32; off > 0; off >>= 1) p += __shfl_down(p, off);
        if (lane == 0) out[t * OUTD + j] = p + br[j];
    }
}

extern "C" void kernel_launch(void* const* d_in, const int* in_sizes, int n_in,
                              void* d_out, int out_size, void* d_ws, size_t ws_size,
                              hipStream_t stream) {
    const float* x  = (const float*)d_in[0];
    const int*   ei = (const int*)d_in[1];
    const int*   tm = (const int*)d_in[2];
    const float* W1 = (const float*)d_in[3];
    const float* b1 = (const float*)d_in[4];
    const float* W2 = (const float*)d_in[5];
    const float* b2 = (const float*)d_in[6];
    const float* Wr = (const float*)d_in[7];
    const float* br = (const float*)d_in[8];
    float* out = (float*)d_out;

    const int* e_src = ei;
    const int* e_dst = ei + N_EDGES;

    // workspace layout — all ranges disjoint:
    //   dinv     [0x000000, 0x030D40)
    //   counts   [0x040000, 0x070D40)
    //   rowptr   [0x080000, 0x0B0D40)
    //   cursor   [0x0C0000, 0x0F0D40)
    //   partials [0x0F8000, 0x0F8310)   <- was 0x0F0000: OVERLAPPED cursor (race!)
    //   col      [0x100000, 0x40D400)
    //   bufA/bufB from 0x500000
    char* ws = (char*)d_ws;
    float* dinv     = (float*)(ws + 0x000000);
    int*   counts   = (int*)  (ws + 0x040000);
    int*   rowptr   = (int*)  (ws + 0x080000);
    int*   cursor   = (int*)  (ws + 0x0C0000);
    int*   partials = (int*)  (ws + 0x0F8000);
    int*   col      = (int*)  (ws + 0x100000);
    float* bufA     = (float*)(ws + 0x500000);
    float* bufB     = (float*)(ws + 0x500000 + (size_t)N_NODES * HID * 4);

    const int NB_E   = (N_EDGES + 255) / 256;
    const int NB_N   = (N_NODES + 255) / 256;
    const int NB_AGG = (N_NODES * 32 + 255) / 256;
    const int NB_G   = (N_NODES + 63) / 64;

    // ---- CSR build (by dst) + dinv ----
    hipMemsetAsync(counts, 0, N_NODES * sizeof(int), stream);
    k_hist<<<NB_E, 256, 0, stream>>>(e_dst, counts, N_EDGES);
    k_scan_part<<<SCAN_NB, 256, 0, stream>>>(counts, partials);
    k_scan_top<<<1, 256, 0, stream>>>(partials);
    k_scan_final<<<SCAN_NB, 256, 0, stream>>>(counts, partials, rowptr, cursor, dinv);
    k_fill<<<NB_E, 256, 0, stream>>>(e_src, e_dst, cursor, col, N_EDGES);
    k_sort_rows<<<NB_N, 256, 0, stream>>>(rowptr, counts, col);

    // ---- layer 1 ----
    k_gemm<EMBED><<<NB_G, 128, 0, stream>>>(x, W1, bufA, N_NODES);
    k_agg_csr<<<NB_AGG, 256, 0, stream>>>(bufA, rowptr, counts, col, dinv, b1, bufB);

    // ---- layer 2 ----
    k_gemm<HID><<<NB_G, 128, 0, stream>>>(bufB, W2, bufA, N_NODES);
    k_agg_csr<<<NB_AGG, 256, 0, stream>>>(bufA, rowptr, counts, col, dinv, b2, bufB);

    // ---- readout ----
    k_final<<<N_TGT, 64, 0, stream>>>(bufB, tm, Wr, br, out);
}

// Round 6
// 346.672 us; speedup vs baseline: 1.2413x; 1.2413x over previous
//
#include <hip/hip_runtime.h>
#include <math.h>

#define N_NODES 50000
#define N_EDGES 800000
#define EMBED 256
#define HID 128
#define OUTD 12
#define N_TGT 4096

#define SCAN_NB 196  // ceil(50000/256)

// ---------------- CSR build ----------------
__global__ void k_hist(const int* __restrict__ dst, int* __restrict__ counts, int nE) {
    int i = blockIdx.x * 256 + threadIdx.x;
    if (i < nE) atomicAdd(&counts[dst[i]], 1);
}

// stage 1: per-block sums of counts
__global__ __launch_bounds__(256) void k_scan_part(const int* __restrict__ counts,
                                                   int* __restrict__ partials) {
    __shared__ int ws[4];
    int i = blockIdx.x * 256 + threadIdx.x;
    int v = (i < N_NODES) ? counts[i] : 0;
#pragma unroll
    for (int off = 32; off > 0; off >>= 1) v += __shfl_down(v, off);
    int wid = threadIdx.x >> 6;
    if ((threadIdx.x & 63) == 0) ws[wid] = v;
    __syncthreads();
    if (threadIdx.x == 0) partials[blockIdx.x] = ws[0] + ws[1] + ws[2] + ws[3];
}

// stage 2: exclusive scan of partials[SCAN_NB] in one small block
__global__ __launch_bounds__(256) void k_scan_top(int* __restrict__ partials) {
    __shared__ int s[256];
    int tid = threadIdx.x;
    int v = (tid < SCAN_NB) ? partials[tid] : 0;
    s[tid] = v;
    __syncthreads();
#pragma unroll
    for (int off = 1; off < 256; off <<= 1) {
        int t = (tid >= off) ? s[tid - off] : 0;
        __syncthreads();
        s[tid] += t;
        __syncthreads();
    }
    if (tid < SCAN_NB) partials[tid] = s[tid] - v;  // exclusive
}

// stage 3: per-block exclusive scan + offset -> rowptr, cursor, dinv
__global__ __launch_bounds__(256) void k_scan_final(const int* __restrict__ counts,
                                                    const int* __restrict__ partials,
                                                    int* __restrict__ rowptr,
                                                    int* __restrict__ cursor,
                                                    float* __restrict__ dinv) {
    __shared__ int s[256];
    int tid = threadIdx.x;
    int i = blockIdx.x * 256 + tid;
    int c = (i < N_NODES) ? counts[i] : 0;
    s[tid] = c;
    __syncthreads();
#pragma unroll
    for (int off = 1; off < 256; off <<= 1) {
        int t = (tid >= off) ? s[tid - off] : 0;
        __syncthreads();
        s[tid] += t;
        __syncthreads();
    }
    if (i < N_NODES) {
        int rp = partials[blockIdx.x] + s[tid] - c;  // exclusive
        rowptr[i] = rp;
        cursor[i] = rp;
        dinv[i] = rsqrtf(1.0f + (float)c);
    }
}

__global__ void k_fill(const int* __restrict__ src, const int* __restrict__ dst,
                       int* __restrict__ cursor, int* __restrict__ col, int nE) {
    int i = blockIdx.x * 256 + threadIdx.x;
    if (i < nE) {
        int pos = atomicAdd(&cursor[dst[i]], 1);
        col[pos] = src[i];
    }
}

// canonicalize: one WAVE per row, 64-lane bitonic sort in registers.
// (atomic fill order is schedule-dependent; sorted rows make the FP sum
// order a deterministic function of the edge set. duplicate values are
// interchangeable-equal so equal-key order doesn't matter.)
__global__ __launch_bounds__(256) void k_sort_rows(const int* __restrict__ rowptr,
                                                   const int* __restrict__ counts,
                                                   int* __restrict__ col) {
    int wid = threadIdx.x >> 6;
    int lane = threadIdx.x & 63;
    int v = blockIdx.x * 4 + wid;          // 12500 blocks * 4 waves = 50000 rows
    if (v >= N_NODES) return;
    int beg = rowptr[v], cnt = counts[v];
    if (cnt <= 1) return;                  // wave-uniform
    if (cnt <= 64) {
        int key = (lane < cnt) ? col[beg + lane] : 0x7FFFFFFF;
#pragma unroll
        for (int k = 2; k <= 64; k <<= 1) {
#pragma unroll
            for (int j = k >> 1; j > 0; j >>= 1) {
                int other = __shfl_xor(key, j);
                bool up = ((lane & k) == 0);
                bool lower = ((lane & j) == 0);
                bool take_min = (lower == up);
                key = take_min ? min(key, other) : max(key, other);
            }
        }
        if (lane < cnt) col[beg + lane] = key;
    } else if (lane == 0) {
        // fallback (essentially never for Poisson(16) rows, kept for correctness)
        for (int i = 1; i < cnt; ++i) {
            int key = col[beg + i];
            int j = i - 1;
            while (j >= 0 && col[beg + j] > key) {
                col[beg + j + 1] = col[beg + j];
                --j;
            }
            col[beg + j + 1] = key;
        }
    }
}

// ---------------- tiled f32 GEMM: H[n][128] = X[n][K] @ W[K][128] ----------------
template <int K>
__global__ __launch_bounds__(128) void k_gemm(const float* __restrict__ X,
                                              const float* __restrict__ W,
                                              float* __restrict__ H, int n) {
    __shared__ float As[32][68];
    __shared__ float Bs[32][132];
    const int tid = threadIdx.x;
    const int row0 = blockIdx.x * 64;
    const int ty = tid >> 4;
    const int tx = tid & 15;
    float acc[8][8] = {};
    for (int k0 = 0; k0 < K; k0 += 32) {
#pragma unroll
        for (int i = 0; i < 4; ++i) {
            int f = tid + i * 128;
            int r = f >> 3, k4 = f & 7;
            float4 v = make_float4(0.f, 0.f, 0.f, 0.f);
            if (row0 + r < n)
                v = *(const float4*)&X[(size_t)(row0 + r) * K + k0 + k4 * 4];
            As[k4 * 4 + 0][r] = v.x;
            As[k4 * 4 + 1][r] = v.y;
            As[k4 * 4 + 2][r] = v.z;
            As[k4 * 4 + 3][r] = v.w;
        }
#pragma unroll
        for (int i = 0; i < 8; ++i) {
            int f = tid + i * 128;
            int kk = f >> 5, c4 = f & 31;
            *(float4*)&Bs[kk][c4 * 4] = *(const float4*)&W[(size_t)(k0 + kk) * 128 + c4 * 4];
        }
        __syncthreads();
#pragma unroll
        for (int k = 0; k < 32; ++k) {
            float4 a0 = *(const float4*)&As[k][ty * 8];
            float4 a1 = *(const float4*)&As[k][ty * 8 + 4];
            float4 b0 = *(const float4*)&Bs[k][tx * 8];
            float4 b1 = *(const float4*)&Bs[k][tx * 8 + 4];
            float a[8] = {a0.x, a0.y, a0.z, a0.w, a1.x, a1.y, a1.z, a1.w};
            float b[8] = {b0.x, b0.y, b0.z, b0.w, b1.x, b1.y, b1.z, b1.w};
#pragma unroll
            for (int i = 0; i < 8; ++i)
#pragma unroll
                for (int j = 0; j < 8; ++j) acc[i][j] = fmaf(a[i], b[j], acc[i][j]);
        }
        __syncthreads();
    }
#pragma unroll
    for (int i = 0; i < 8; ++i) {
        int r = row0 + ty * 8 + i;
        if (r < n) {
            *(float4*)&H[(size_t)r * 128 + tx * 8] =
                make_float4(acc[i][0], acc[i][1], acc[i][2], acc[i][3]);
            *(float4*)&H[(size_t)r * 128 + tx * 8 + 4] =
                make_float4(acc[i][4], acc[i][5], acc[i][6], acc[i][7]);
        }
    }
}

// ---------------- fused CSR aggregation + self-loop + bias + ReLU ----------------
__global__ __launch_bounds__(256) void k_agg_csr(const float* __restrict__ h,
                                                 const int* __restrict__ rowptr,
                                                 const int* __restrict__ counts,
                                                 const int* __restrict__ col,
                                                 const float* __restrict__ dinv,
                                                 const float* __restrict__ b,
                                                 float* __restrict__ out) {
    int t = blockIdx.x * 256 + threadIdx.x;
    int v = t >> 5;
    int lane = t & 31;
    if (v >= N_NODES) return;
    float dv = dinv[v];
    float4 hv = *(const float4*)&h[(size_t)v * HID + lane * 4];
    float sl = dv * dv;
    float4 acc = make_float4(hv.x * sl, hv.y * sl, hv.z * sl, hv.w * sl);
    int beg = rowptr[v];
    int cnt = counts[v];
    for (int j = 0; j < cnt; ++j) {
        int s = col[beg + j];
        float w = dinv[s] * dv;
        float4 m = *(const float4*)&h[(size_t)s * HID + lane * 4];
        acc.x = fmaf(m.x, w, acc.x);
        acc.y = fmaf(m.y, w, acc.y);
        acc.z = fmaf(m.z, w, acc.z);
        acc.w = fmaf(m.w, w, acc.w);
    }
    float4 bv = *(const float4*)&b[lane * 4];
    acc.x = fmaxf(acc.x + bv.x, 0.f);
    acc.y = fmaxf(acc.y + bv.y, 0.f);
    acc.z = fmaxf(acc.z + bv.z, 0.f);
    acc.w = fmaxf(acc.w + bv.w, 0.f);
    *(float4*)&out[(size_t)v * HID + lane * 4] = acc;
}

// ---------------- final readout ----------------
__global__ void k_final(const float* __restrict__ h, const int* __restrict__ mask,
                        const float* __restrict__ Wr, const float* __restrict__ br,
                        float* __restrict__ out) {
    int t = blockIdx.x;
    int lane = threadIdx.x;
    int node = mask[t];
    float2 hv = *(const float2*)&h[(size_t)node * HID + lane * 2];
#pragma unroll
    for (int j = 0; j < OUTD; ++j) {
        float p = hv.x * Wr[(lane * 2) * OUTD + j] + hv.y * Wr[(lane * 2 + 1) * OUTD + j];
#pragma unroll
        for (int off = 32; off > 0; off >>= 1) p += __shfl_down(p, off);
        if (lane == 0) out[t * OUTD + j] = p + br[j];
    }
}

extern "C" void kernel_launch(void* const* d_in, const int* in_sizes, int n_in,
                              void* d_out, int out_size, void* d_ws, size_t ws_size,
                              hipStream_t stream) {
    const float* x  = (const float*)d_in[0];
    const int*   ei = (const int*)d_in[1];
    const int*   tm = (const int*)d_in[2];
    const float* W1 = (const float*)d_in[3];
    const float* b1 = (const float*)d_in[4];
    const float* W2 = (const float*)d_in[5];
    const float* b2 = (const float*)d_in[6];
    const float* Wr = (const float*)d_in[7];
    const float* br = (const float*)d_in[8];
    float* out = (float*)d_out;

    const int* e_src = ei;
    const int* e_dst = ei + N_EDGES;

    // workspace layout — all ranges disjoint:
    //   dinv     [0x000000, 0x030D40)
    //   counts   [0x040000, 0x070D40)
    //   rowptr   [0x080000, 0x0B0D40)
    //   cursor   [0x0C0000, 0x0F0D40)
    //   partials [0x0F8000, 0x0F8310)
    //   col      [0x100000, 0x40D400)
    //   bufA/bufB from 0x500000
    char* ws = (char*)d_ws;
    float* dinv     = (float*)(ws + 0x000000);
    int*   counts   = (int*)  (ws + 0x040000);
    int*   rowptr   = (int*)  (ws + 0x080000);
    int*   cursor   = (int*)  (ws + 0x0C0000);
    int*   partials = (int*)  (ws + 0x0F8000);
    int*   col      = (int*)  (ws + 0x100000);
    float* bufA     = (float*)(ws + 0x500000);
    float* bufB     = (float*)(ws + 0x500000 + (size_t)N_NODES * HID * 4);

    const int NB_E   = (N_EDGES + 255) / 256;
    const int NB_AGG = (N_NODES * 32 + 255) / 256;
    const int NB_G   = (N_NODES + 63) / 64;
    const int NB_SORT = (N_NODES + 3) / 4;   // 4 waves (rows) per block

    // ---- CSR build (by dst) + dinv ----
    hipMemsetAsync(counts, 0, N_NODES * sizeof(int), stream);
    k_hist<<<NB_E, 256, 0, stream>>>(e_dst, counts, N_EDGES);
    k_scan_part<<<SCAN_NB, 256, 0, stream>>>(counts, partials);
    k_scan_top<<<1, 256, 0, stream>>>(partials);
    k_scan_final<<<SCAN_NB, 256, 0, stream>>>(counts, partials, rowptr, cursor, dinv);
    k_fill<<<NB_E, 256, 0, stream>>>(e_src, e_dst, cursor, col, N_EDGES);
    k_sort_rows<<<NB_SORT, 256, 0, stream>>>(rowptr, counts, col);

    // ---- layer 1 ----
    k_gemm<EMBED><<<NB_G, 128, 0, stream>>>(x, W1, bufA, N_NODES);
    k_agg_csr<<<NB_AGG, 256, 0, stream>>>(bufA, rowptr, counts, col, dinv, b1, bufB);

    // ---- layer 2 ----
    k_gemm<HID><<<NB_G, 128, 0, stream>>>(bufB, W2, bufA, N_NODES);
    k_agg_csr<<<NB_AGG, 256, 0, stream>>>(bufA, rowptr, counts, col, dinv, b2, bufB);

    // ---- readout ----
    k_final<<<N_TGT, 64, 0, stream>>>(bufB, tm, Wr, br, out);
}

// Round 7
// 303.167 us; speedup vs baseline: 1.4194x; 1.1435x over previous
//
#include <hip/hip_runtime.h>
#include <math.h>

#define N_NODES 50000
#define N_EDGES 800000
#define EMBED 256
#define HID 128
#define OUTD 12
#define N_TGT 4096

#define SCAN_NB 196  // ceil(50000/256)

typedef short bf16x8 __attribute__((ext_vector_type(8)));
typedef float f32x4 __attribute__((ext_vector_type(4)));

// f32 -> bf16 round-to-nearest-even (bit-exact, deterministic)
__device__ __forceinline__ unsigned short f2b(float f) {
    union { float f; unsigned int u; } v;
    v.f = f;
    unsigned int u = v.u;
    return (unsigned short)((u + 0x7FFFu + ((u >> 16) & 1u)) >> 16);
}

// ---------------- CSR build ----------------
__global__ void k_hist(const int* __restrict__ dst, int* __restrict__ counts, int nE) {
    int i = blockIdx.x * 256 + threadIdx.x;
    if (i < nE) atomicAdd(&counts[dst[i]], 1);
}

__global__ __launch_bounds__(256) void k_scan_part(const int* __restrict__ counts,
                                                   int* __restrict__ partials) {
    __shared__ int ws[4];
    int i = blockIdx.x * 256 + threadIdx.x;
    int v = (i < N_NODES) ? counts[i] : 0;
#pragma unroll
    for (int off = 32; off > 0; off >>= 1) v += __shfl_down(v, off);
    int wid = threadIdx.x >> 6;
    if ((threadIdx.x & 63) == 0) ws[wid] = v;
    __syncthreads();
    if (threadIdx.x == 0) partials[blockIdx.x] = ws[0] + ws[1] + ws[2] + ws[3];
}

__global__ __launch_bounds__(256) void k_scan_top(int* __restrict__ partials) {
    __shared__ int s[256];
    int tid = threadIdx.x;
    int v = (tid < SCAN_NB) ? partials[tid] : 0;
    s[tid] = v;
    __syncthreads();
#pragma unroll
    for (int off = 1; off < 256; off <<= 1) {
        int t = (tid >= off) ? s[tid - off] : 0;
        __syncthreads();
        s[tid] += t;
        __syncthreads();
    }
    if (tid < SCAN_NB) partials[tid] = s[tid] - v;  // exclusive
}

__global__ __launch_bounds__(256) void k_scan_final(const int* __restrict__ counts,
                                                    const int* __restrict__ partials,
                                                    int* __restrict__ rowptr,
                                                    int* __restrict__ cursor,
                                                    float* __restrict__ dinv) {
    __shared__ int s[256];
    int tid = threadIdx.x;
    int i = blockIdx.x * 256 + tid;
    int c = (i < N_NODES) ? counts[i] : 0;
    s[tid] = c;
    __syncthreads();
#pragma unroll
    for (int off = 1; off < 256; off <<= 1) {
        int t = (tid >= off) ? s[tid - off] : 0;
        __syncthreads();
        s[tid] += t;
        __syncthreads();
    }
    if (i < N_NODES) {
        int rp = partials[blockIdx.x] + s[tid] - c;  // exclusive
        rowptr[i] = rp;
        cursor[i] = rp;
        dinv[i] = rsqrtf(1.0f + (float)c);
    }
}

__global__ void k_fill(const int* __restrict__ src, const int* __restrict__ dst,
                       int* __restrict__ cursor, int* __restrict__ col, int nE) {
    int i = blockIdx.x * 256 + threadIdx.x;
    if (i < nE) {
        int pos = atomicAdd(&cursor[dst[i]], 1);
        col[pos] = src[i];
    }
}

// one WAVE per row, 64-lane bitonic sort in registers (determinism canonicalizer)
__global__ __launch_bounds__(256) void k_sort_rows(const int* __restrict__ rowptr,
                                                   const int* __restrict__ counts,
                                                   int* __restrict__ col) {
    int wid = threadIdx.x >> 6;
    int lane = threadIdx.x & 63;
    int v = blockIdx.x * 4 + wid;
    if (v >= N_NODES) return;
    int beg = rowptr[v], cnt = counts[v];
    if (cnt <= 1) return;
    if (cnt <= 64) {
        int key = (lane < cnt) ? col[beg + lane] : 0x7FFFFFFF;
#pragma unroll
        for (int k = 2; k <= 64; k <<= 1) {
#pragma unroll
            for (int j = k >> 1; j > 0; j >>= 1) {
                int other = __shfl_xor(key, j);
                bool up = ((lane & k) == 0);
                bool lower = ((lane & j) == 0);
                bool take_min = (lower == up);
                key = take_min ? min(key, other) : max(key, other);
            }
        }
        if (lane < cnt) col[beg + lane] = key;
    } else if (lane == 0) {
        for (int i = 1; i < cnt; ++i) {
            int key = col[beg + i];
            int j = i - 1;
            while (j >= 0 && col[beg + j] > key) {
                col[beg + j + 1] = col[beg + j];
                --j;
            }
            col[beg + j + 1] = key;
        }
    }
}

// ---------------- W[k][n] f32 -> Wt[n][k] bf16 (tiny, once per launch) ----------------
__global__ void k_convW(const float* __restrict__ W, unsigned short* __restrict__ Wt, int K) {
    int i = blockIdx.x * 256 + threadIdx.x;
    if (i >= 128 * K) return;
    int n = i / K;
    int k = i - n * K;
    Wt[(size_t)n * K + k] = f2b(W[(size_t)k * 128 + n]);
}

// ---------------- bf16 MFMA GEMM: H[n][128] = X[n][K] @ W[K][128] ----------------
// 256 threads = 4 waves (2x2), tile 128x128, BK=32. A staged to LDS (f32->bf16
// in-register, padded stride 40 bf16 -> conflict-free ds_read_b128). B frags
// read directly from L2-hot Wt[n][k]. C/D layout: col=lane&15, row=(lane>>4)*4+reg.
template <int K>
__global__ __launch_bounds__(256) void k_gemm_mfma(const float* __restrict__ X,
                                                   const unsigned short* __restrict__ Wt,
                                                   float* __restrict__ H, int n) {
    __shared__ unsigned short As[128 * 40];
    const int tid = threadIdx.x;
    const int row0 = blockIdx.x * 128;
    const int w = tid >> 6, lane = tid & 63;
    const int wm = w >> 1, wn = w & 1;
    const int lr = lane & 15, lg = lane >> 4;
    f32x4 acc[4][4] = {};
    for (int k0 = 0; k0 < K; k0 += 32) {
        __syncthreads();  // protect previous tile's frag reads
#pragma unroll
        for (int i = 0; i < 4; ++i) {
            int s = i * 256 + tid;          // 0..1023 float4 slots (128 rows x 8)
            int r = s >> 3, c4 = (s & 7) * 4;
            int gr = row0 + r;
            float4 v = make_float4(0.f, 0.f, 0.f, 0.f);
            if (gr < n) v = *(const float4*)&X[(size_t)gr * K + k0 + c4];
            ushort4 pk = make_ushort4(f2b(v.x), f2b(v.y), f2b(v.z), f2b(v.w));
            *(ushort4*)&As[r * 40 + c4] = pk;
        }
        __syncthreads();
        bf16x8 bfr[4];
#pragma unroll
        for (int fn = 0; fn < 4; ++fn) {
            int colg = wn * 64 + fn * 16 + lr;
            bfr[fn] = *(const bf16x8*)&Wt[(size_t)colg * K + k0 + lg * 8];
        }
#pragma unroll
        for (int fm = 0; fm < 4; ++fm) {
            int rloc = wm * 64 + fm * 16 + lr;
            bf16x8 afr = *(const bf16x8*)&As[rloc * 40 + lg * 8];
#pragma unroll
            for (int fn = 0; fn < 4; ++fn)
                acc[fm][fn] = __builtin_amdgcn_mfma_f32_16x16x32_bf16(
                    afr, bfr[fn], acc[fm][fn], 0, 0, 0);
        }
    }
#pragma unroll
    for (int fm = 0; fm < 4; ++fm) {
        int rbase = row0 + wm * 64 + fm * 16 + lg * 4;
#pragma unroll
        for (int r = 0; r < 4; ++r) {
            int gr = rbase + r;
            if (gr < n) {
#pragma unroll
                for (int fn = 0; fn < 4; ++fn)
                    H[(size_t)gr * 128 + wn * 64 + fn * 16 + lr] = acc[fm][fn][r];
            }
        }
    }
}

// ---------------- fused CSR aggregation + self-loop + bias + ReLU ----------------
__global__ __launch_bounds__(256) void k_agg_csr(const float* __restrict__ h,
                                                 const int* __restrict__ rowptr,
                                                 const int* __restrict__ counts,
                                                 const int* __restrict__ col,
                                                 const float* __restrict__ dinv,
                                                 const float* __restrict__ b,
                                                 float* __restrict__ out) {
    int t = blockIdx.x * 256 + threadIdx.x;
    int v = t >> 5;
    int lane = t & 31;
    if (v >= N_NODES) return;
    float dv = dinv[v];
    float4 hv = *(const float4*)&h[(size_t)v * HID + lane * 4];
    float sl = dv * dv;
    float4 acc = make_float4(hv.x * sl, hv.y * sl, hv.z * sl, hv.w * sl);
    int beg = rowptr[v];
    int cnt = counts[v];
    for (int j = 0; j < cnt; ++j) {
        int s = col[beg + j];
        float w = dinv[s] * dv;
        float4 m = *(const float4*)&h[(size_t)s * HID + lane * 4];
        acc.x = fmaf(m.x, w, acc.x);
        acc.y = fmaf(m.y, w, acc.y);
        acc.z = fmaf(m.z, w, acc.z);
        acc.w = fmaf(m.w, w, acc.w);
    }
    float4 bv = *(const float4*)&b[lane * 4];
    acc.x = fmaxf(acc.x + bv.x, 0.f);
    acc.y = fmaxf(acc.y + bv.y, 0.f);
    acc.z = fmaxf(acc.z + bv.z, 0.f);
    acc.w = fmaxf(acc.w + bv.w, 0.f);
    *(float4*)&out[(size_t)v * HID + lane * 4] = acc;
}

// ---------------- final readout ----------------
__global__ void k_final(const float* __restrict__ h, const int* __restrict__ mask,
                        const float* __restrict__ Wr, const float* __restrict__ br,
                        float* __restrict__ out) {
    int t = blockIdx.x;
    int lane = threadIdx.x;
    int node = mask[t];
    float2 hv = *(const float2*)&h[(size_t)node * HID + lane * 2];
#pragma unroll
    for (int j = 0; j < OUTD; ++j) {
        float p = hv.x * Wr[(lane * 2) * OUTD + j] + hv.y * Wr[(lane * 2 + 1) * OUTD + j];
#pragma unroll
        for (int off = 32; off > 0; off >>= 1) p += __shfl_down(p, off);
        if (lane == 0) out[t * OUTD + j] = p + br[j];
    }
}

extern "C" void kernel_launch(void* const* d_in, const int* in_sizes, int n_in,
                              void* d_out, int out_size, void* d_ws, size_t ws_size,
                              hipStream_t stream) {
    const float* x  = (const float*)d_in[0];
    const int*   ei = (const int*)d_in[1];
    const int*   tm = (const int*)d_in[2];
    const float* W1 = (const float*)d_in[3];
    const float* b1 = (const float*)d_in[4];
    const float* W2 = (const float*)d_in[5];
    const float* b2 = (const float*)d_in[6];
    const float* Wr = (const float*)d_in[7];
    const float* br = (const float*)d_in[8];
    float* out = (float*)d_out;

    const int* e_src = ei;
    const int* e_dst = ei + N_EDGES;

    // workspace layout — all ranges disjoint:
    //   dinv     [0x000000, 0x030D40)
    //   counts   [0x040000, 0x070D40)
    //   rowptr   [0x080000, 0x0B0D40)
    //   cursor   [0x0C0000, 0x0F0D40)
    //   partials [0x0F8000, 0x0F8310)
    //   col      [0x100000, 0x40D400)
    //   Wt1      [0x410000, 0x420000)  128x256 bf16
    //   Wt2      [0x430000, 0x438000)  128x128 bf16
    //   bufA/bufB from 0x500000
    char* ws = (char*)d_ws;
    float*          dinv     = (float*)(ws + 0x000000);
    int*            counts   = (int*)  (ws + 0x040000);
    int*            rowptr   = (int*)  (ws + 0x080000);
    int*            cursor   = (int*)  (ws + 0x0C0000);
    int*            partials = (int*)  (ws + 0x0F8000);
    int*            col      = (int*)  (ws + 0x100000);
    unsigned short* Wt1      = (unsigned short*)(ws + 0x410000);
    unsigned short* Wt2      = (unsigned short*)(ws + 0x430000);
    float*          bufA     = (float*)(ws + 0x500000);
    float*          bufB     = (float*)(ws + 0x500000 + (size_t)N_NODES * HID * 4);

    const int NB_E    = (N_EDGES + 255) / 256;
    const int NB_AGG  = (N_NODES * 32 + 255) / 256;
    const int NB_MF   = (N_NODES + 127) / 128;
    const int NB_SORT = (N_NODES + 3) / 4;

    // ---- CSR build (by dst) + dinv + weight conversion ----
    hipMemsetAsync(counts, 0, N_NODES * sizeof(int), stream);
    k_hist<<<NB_E, 256, 0, stream>>>(e_dst, counts, N_EDGES);
    k_scan_part<<<SCAN_NB, 256, 0, stream>>>(counts, partials);
    k_scan_top<<<1, 256, 0, stream>>>(partials);
    k_scan_final<<<SCAN_NB, 256, 0, stream>>>(counts, partials, rowptr, cursor, dinv);
    k_fill<<<NB_E, 256, 0, stream>>>(e_src, e_dst, cursor, col, N_EDGES);
    k_sort_rows<<<NB_SORT, 256, 0, stream>>>(rowptr, counts, col);
    k_convW<<<(128 * EMBED + 255) / 256, 256, 0, stream>>>(W1, Wt1, EMBED);
    k_convW<<<(128 * HID + 255) / 256, 256, 0, stream>>>(W2, Wt2, HID);

    // ---- layer 1 ----
    k_gemm_mfma<EMBED><<<NB_MF, 256, 0, stream>>>(x, Wt1, bufA, N_NODES);
    k_agg_csr<<<NB_AGG, 256, 0, stream>>>(bufA, rowptr, counts, col, dinv, b1, bufB);

    // ---- layer 2 ----
    k_gemm_mfma<HID><<<NB_MF, 256, 0, stream>>>(bufB, Wt2, bufA, N_NODES);
    k_agg_csr<<<NB_AGG, 256, 0, stream>>>(bufA, rowptr, counts, col, dinv, b2, bufB);

    // ---- readout ----
    k_final<<<N_TGT, 64, 0, stream>>>(bufB, tm, Wr, br, out);
}